// Round 1
// baseline (183.065 us; speedup 1.0000x reference)
//
#include <hip/hip_runtime.h>
#include <hip/hip_bf16.h>
#include <cstdint>

// ---------------------------------------------------------------------------
// GAT forward, N=4096, F=512, D=64, H=8, O=128, fp32 in/out.
// Strategy:
//   adj -> bitmask (2MB, L2-resident)
//   Wh = x @ W        : bf16 MFMA GEMM (fp32 accum, fp32 out)
//   s1/s2 = Wh @ a1/a2: wave-per-row dot, pre-scaled by log2(e)
//   h_i = sum_j adj_ij * exp(lrelu(s1_i+s2_j)) * Wh_j / Z_i
//        -> fused kernel: P-tile generated in-register (rank-1 logits),
//           A-frag = P (bf16), B-frag = Wh^T (bf16, direct from L2),
//           mfma_f32_16x16x32_bf16, fp32 partials + separate finalize.
// No softmax max-subtraction: |e| <= ~5, exp safe in fp32; masked -> p=0.
// ---------------------------------------------------------------------------

using bf16_t = __bf16;
using bf16x8 = __attribute__((ext_vector_type(8))) __bf16;
using f32x4  = __attribute__((ext_vector_type(4))) float;

#define LOG2E 1.44269504f

// ---- pack adjacency into bitmask: bit j of word [i][j/32] = (adj[i][j] > 0)
__global__ __launch_bounds__(256) void pack_bits_k(const int* __restrict__ adj,
                                                   uint32_t* __restrict__ bits, int total) {
    int stride = gridDim.x * blockDim.x;
    for (int idx = blockIdx.x * blockDim.x + threadIdx.x; idx < total; idx += stride) {
        unsigned long long m = __ballot(adj[idx] > 0);
        int l = threadIdx.x & 63;
        if (l == 0)        bits[idx >> 5] = (uint32_t)m;
        else if (l == 32)  bits[idx >> 5] = (uint32_t)(m >> 32);
    }
}

// ---- flat fp32 -> bf16
__global__ __launch_bounds__(256) void cvt_bf16_k(const float* __restrict__ src,
                                                  bf16_t* __restrict__ dst, int n) {
    int stride = gridDim.x * blockDim.x;
    for (int i = blockIdx.x * blockDim.x + threadIdx.x; i < n; i += stride)
        dst[i] = (bf16_t)src[i];
}

// ---- transpose + convert: src [R][C] fp32 (slice z) -> dst [C][R] bf16
__global__ __launch_bounds__(256) void transpose_cvt_k(const float* __restrict__ src,
                                                       bf16_t* __restrict__ dst, int R, int C) {
    src += (size_t)blockIdx.z * R * C;
    dst += (size_t)blockIdx.z * R * C;
    int r = blockIdx.x * 256 + threadIdx.x;
    int c = blockIdx.y;
    if (r < R) dst[(size_t)c * R + r] = (bf16_t)src[(size_t)r * C + c];
}

// ---- bf16 MFMA GEMM: C[M][NC] fp32 = A[M][K] * BT[NC][K]^T
// wave(64thr) computes 32 rows x 64 cols. grid (M/32, NC/64).
__global__ __launch_bounds__(64) void gemm_bf16_k(const bf16_t* __restrict__ A,
                                                  const bf16_t* __restrict__ BT,
                                                  float* __restrict__ C, int M, int K, int NC) {
    int lane = threadIdx.x;
    int lr = lane & 15, kg = lane >> 4;
    int rowb = blockIdx.x * 32, cb = blockIdx.y * 64;
    f32x4 acc[2][4];
#pragma unroll
    for (int rt = 0; rt < 2; ++rt)
#pragma unroll
        for (int dt = 0; dt < 4; ++dt) acc[rt][dt] = 0.0f;

    for (int k0 = 0; k0 < K; k0 += 32) {
        bf16x8 af[2], bfr[4];
#pragma unroll
        for (int rt = 0; rt < 2; ++rt)
            af[rt] = *(const bf16x8*)(A + (size_t)(rowb + rt * 16 + lr) * K + k0 + kg * 8);
#pragma unroll
        for (int dt = 0; dt < 4; ++dt)
            bfr[dt] = *(const bf16x8*)(BT + (size_t)(cb + dt * 16 + lr) * K + k0 + kg * 8);
#pragma unroll
        for (int rt = 0; rt < 2; ++rt)
#pragma unroll
            for (int dt = 0; dt < 4; ++dt)
                acc[rt][dt] = __builtin_amdgcn_mfma_f32_16x16x32_bf16(af[rt], bfr[dt], acc[rt][dt], 0, 0, 0);
    }
#pragma unroll
    for (int rt = 0; rt < 2; ++rt)
#pragma unroll
        for (int dt = 0; dt < 4; ++dt)
#pragma unroll
            for (int r = 0; r < 4; ++r)
                C[(size_t)(rowb + rt * 16 + kg * 4 + r) * NC + cb + dt * 16 + lr] = acc[rt][dt][r];
}

// ---- s1/s2: per (head,row) dots with a1/a2, pre-scaled by log2(e)
__global__ __launch_bounds__(256) void s_kernel(const float* __restrict__ Wh,
                                                const float* __restrict__ a1,
                                                const float* __restrict__ a2,
                                                float* __restrict__ s1, float* __restrict__ s2,
                                                int Nn, int CT, int D, int H) {
    int w = (blockIdx.x * blockDim.x + threadIdx.x) >> 6;
    int lane = threadIdx.x & 63;
    if (w >= Nn * H) return;
    int i = w % Nn, h = w / Nn;
    float sum1 = 0.f, sum2 = 0.f;
    for (int d = lane; d < D; d += 64) {
        float v = Wh[(size_t)i * CT + h * D + d];
        sum1 += v * a1[h * D + d];
        sum2 += v * a2[h * D + d];
    }
#pragma unroll
    for (int o = 32; o > 0; o >>= 1) {
        sum1 += __shfl_down(sum1, o);
        sum2 += __shfl_down(sum2, o);
    }
    if (lane == 0) {
        s1[(size_t)h * Nn + i] = sum1 * LOG2E;
        s2[(size_t)h * Nn + i] = sum2 * LOG2E;
    }
}

// ---- fused attention-aggregate:
// wave = 64 rows x 64 cols (col-group c), j-range [jz*JR, (jz+1)*JR)
// Hpart[jz][row][CT] += P*V ; zpart[jz*C+c][row] = row-sums of P
__global__ __launch_bounds__(64) void gat_agg_k(const float* __restrict__ s1,
                                                const float* __restrict__ s2, int sstride,
                                                const uint32_t* __restrict__ bits,
                                                const bf16_t* __restrict__ VT,
                                                float* __restrict__ Hpart, float* __restrict__ zpart,
                                                int Nn, int CT, int JR) {
    const int lane = threadIdx.x;
    const int lr = lane & 15, kg = lane >> 4;
    const int rowb = blockIdx.x * 64;
    const int c = blockIdx.y;
    const int jz = blockIdx.z;
    const int C = gridDim.y;
    const int cb = c * 64;
    const float* s1p = s1 + (size_t)sstride * c;
    const float* s2p = s2 + (size_t)sstride * c;
    const int jb0 = jz * JR;
    const int steps = JR / 32;
    const int wpr = Nn >> 5;

    f32x4 acc[4][4];
#pragma unroll
    for (int rt = 0; rt < 4; ++rt)
#pragma unroll
        for (int dt = 0; dt < 4; ++dt) acc[rt][dt] = 0.0f;
    float zacc[4] = {0.f, 0.f, 0.f, 0.f};
    float s1v[4];
    int rows[4];
#pragma unroll
    for (int rt = 0; rt < 4; ++rt) {
        rows[rt] = rowb + rt * 16 + lr;
        s1v[rt] = s1p[rows[rt]];
    }

    for (int js = 0; js < steps; ++js) {
        const int jb = jb0 + js * 32;
        const int jk = jb + kg * 8;
        f32x4 s2a = *(const f32x4*)(s2p + jk);
        f32x4 s2b = *(const f32x4*)(s2p + jk + 4);
        bf16x8 bfr[4];
#pragma unroll
        for (int dt = 0; dt < 4; ++dt)
            bfr[dt] = *(const bf16x8*)(VT + (size_t)(cb + dt * 16 + lr) * Nn + jk);
#pragma unroll
        for (int rt = 0; rt < 4; ++rt) {
            uint32_t w = bits[(size_t)rows[rt] * wpr + (jb >> 5)];
            uint32_t mb = (w >> (kg * 8)) & 0xffu;
            bf16x8 af;
            float zs = 0.f;
#pragma unroll
            for (int e = 0; e < 8; ++e) {
                float s2v = (e < 4) ? s2a[e] : s2b[e - 4];
                float u = s1v[rt] + s2v;          // already log2e-scaled
                float m = fmaxf(u, 0.2f * u);     // leakyrelu (scale-commutes)
                float p = ((mb >> e) & 1u) ? exp2f(m) : 0.0f;
                zs += p;
                af[e] = (bf16_t)p;
            }
            zacc[rt] += zs;
#pragma unroll
            for (int dt = 0; dt < 4; ++dt)
                acc[rt][dt] = __builtin_amdgcn_mfma_f32_16x16x32_bf16(af, bfr[dt], acc[rt][dt], 0, 0, 0);
        }
    }

    float* Hp = Hpart + (size_t)jz * Nn * CT;
#pragma unroll
    for (int rt = 0; rt < 4; ++rt) {
        float z = zacc[rt];
        z += __shfl_xor(z, 16);
        z += __shfl_xor(z, 32);
        if (lane < 16) zpart[(size_t)(jz * C + c) * Nn + rowb + rt * 16 + lr] = z;
#pragma unroll
        for (int dt = 0; dt < 4; ++dt)
#pragma unroll
            for (int r = 0; r < 4; ++r)
                Hp[(size_t)(rowb + rt * 16 + kg * 4 + r) * CT + cb + dt * 16 + lr] = acc[rt][dt][r];
    }
}

// ---- finalize layer 1: hcatb = bf16(ELU(sum_j H / sum_j Z))
__global__ __launch_bounds__(256) void fin1_k(const float* __restrict__ Hpart,
                                              const float* __restrict__ zpart,
                                              bf16_t* __restrict__ hcatb, int Nn) {
    int idx = blockIdx.x * 256 + threadIdx.x;   // < N*512
    int i = idx >> 9, col = idx & 511, h = col >> 6;
    float Hs = 0.f, Z = 0.f;
#pragma unroll
    for (int jz = 0; jz < 4; ++jz) {
        Hs += Hpart[((size_t)jz * Nn + i) * 512 + col];
        Z  += zpart[(size_t)(jz * 8 + h) * Nn + i];
    }
    float v = Hs / Z;
    hcatb[idx] = (bf16_t)(v > 0.f ? v : expm1f(v));
}

// ---- finalize layer 2: out = sum H / sum Z (fp32, no ELU)
__global__ __launch_bounds__(256) void fin2_k(const float* __restrict__ Hpart,
                                              const float* __restrict__ zpart,
                                              float* __restrict__ out, int Nn) {
    int idx = blockIdx.x * 256 + threadIdx.x;   // < N*128
    int i = idx >> 7, o = idx & 127;
    float Hs = 0.f, Z = 0.f;
#pragma unroll
    for (int jz = 0; jz < 16; ++jz) {
        Hs += Hpart[((size_t)jz * Nn + i) * 128 + o];
        Z  += zpart[(size_t)(jz * 2 + 0) * Nn + i];
    }
    out[idx] = Hs / Z;
}

extern "C" void kernel_launch(void* const* d_in, const int* in_sizes, int n_in,
                              void* d_out, int out_size, void* d_ws, size_t ws_size,
                              hipStream_t stream) {
    const int N = 4096, F = 512, D = 64, H = 8, O = 128;
    const int CT1 = H * D;      // 512
    const float* x       = (const float*)d_in[0];
    const int*   adj     = (const int*)d_in[1];
    const float* W_heads = (const float*)d_in[2];
    const float* a1h     = (const float*)d_in[3];
    const float* a2h     = (const float*)d_in[4];
    const float* W_out   = (const float*)d_in[5];
    const float* a1o     = (const float*)d_in[6];
    const float* a2o     = (const float*)d_in[7];

    // workspace layout
    size_t off = 0;
    auto alloc = [&](size_t bytes) { size_t o = off; off = (off + bytes + 255) & ~(size_t)255; return o; };
    char* ws = (char*)d_ws;
    uint32_t* bits  = (uint32_t*)(ws + alloc((size_t)N * N / 8));            // 2 MB
    bf16_t* xb      = (bf16_t*)(ws + alloc((size_t)N * F * 2));              // 4 MB
    bf16_t* WT1     = (bf16_t*)(ws + alloc((size_t)CT1 * F * 2));            // 0.5 MB
    float*  Whcat   = (float*)(ws + alloc((size_t)N * CT1 * 4));             // 8 MB
    float*  s1h     = (float*)(ws + alloc((size_t)H * N * 4));
    float*  s2h     = (float*)(ws + alloc((size_t)H * N * 4));
    bf16_t* VT1     = (bf16_t*)(ws + alloc((size_t)CT1 * N * 2));            // 4 MB
    bf16_t* hcatb   = (bf16_t*)(ws + alloc((size_t)N * CT1 * 2));            // 4 MB
    bf16_t* WoutT   = (bf16_t*)(ws + alloc((size_t)O * CT1 * 2));
    float*  Whout   = (float*)(ws + alloc((size_t)N * O * 4));               // 2 MB
    float*  s1o     = (float*)(ws + alloc((size_t)N * 4));
    float*  s2o     = (float*)(ws + alloc((size_t)N * 4));
    bf16_t* VT2     = (bf16_t*)(ws + alloc((size_t)O * N * 2));              // 1 MB
    float*  zpart   = (float*)(ws + alloc((size_t)32 * N * 4));              // 0.5 MB
    float*  Hpart   = (float*)(ws + alloc((size_t)32 * 1024 * 1024));        // 32 MB
    (void)ws_size; (void)in_sizes; (void)n_in; (void)out_size;

    // 1. adjacency bitmask
    hipLaunchKernelGGL(pack_bits_k, dim3(2048), dim3(256), 0, stream, adj, bits, N * N);
    // 2. x -> bf16
    hipLaunchKernelGGL(cvt_bf16_k, dim3(2048), dim3(256), 0, stream, x, xb, N * F);
    // 3. W_heads [H][F][D] -> WT1 [(h*64+d)][F]
    hipLaunchKernelGGL(transpose_cvt_k, dim3(2, D, H), dim3(256), 0, stream, W_heads, WT1, F, D);
    // 4. Whcat = x @ Wcat   [N][512]
    hipLaunchKernelGGL(gemm_bf16_k, dim3(N / 32, CT1 / 64), dim3(64), 0, stream, xb, WT1, Whcat, N, F, CT1);
    // 5. s1h/s2h
    hipLaunchKernelGGL(s_kernel, dim3(N * H / 4), dim3(256), 0, stream, Whcat, a1h, a2h, s1h, s2h, N, CT1, D, H);
    // 6. VT1 = Whcat^T bf16
    hipLaunchKernelGGL(transpose_cvt_k, dim3(16, CT1, 1), dim3(256), 0, stream, Whcat, VT1, N, CT1);
    // 7. layer-1 aggregate: grid (rowtiles, heads, jsplit=4)
    hipLaunchKernelGGL(gat_agg_k, dim3(N / 64, H, 4), dim3(64), 0, stream,
                       s1h, s2h, N, bits, VT1, Hpart, zpart, N, CT1, N / 4);
    // 8. finalize 1 -> hcatb (bf16)
    hipLaunchKernelGGL(fin1_k, dim3(N * CT1 / 256), dim3(256), 0, stream, Hpart, zpart, hcatb, N);
    // 9. W_out [512][128] -> WoutT [128][512]
    hipLaunchKernelGGL(transpose_cvt_k, dim3(2, O, 1), dim3(256), 0, stream, W_out, WoutT, CT1, O);
    // 10. Whout = hcat @ W_out  [N][128]
    hipLaunchKernelGGL(gemm_bf16_k, dim3(N / 32, O / 64), dim3(64), 0, stream, hcatb, WoutT, Whout, N, CT1, O);
    // 11. s1o/s2o
    hipLaunchKernelGGL(s_kernel, dim3(N / 4), dim3(256), 0, stream, Whout, a1o, a2o, s1o, s2o, N, O, O, 1);
    // 12. VT2 = Whout^T bf16
    hipLaunchKernelGGL(transpose_cvt_k, dim3(16, O, 1), dim3(256), 0, stream, Whout, VT2, N, O);
    // 13. layer-2 aggregate: grid (rowtiles, 2 colgroups, jsplit=16), shared s (sstride=0)
    hipLaunchKernelGGL(gat_agg_k, dim3(N / 64, 2, 16), dim3(64), 0, stream,
                       s1o, s2o, 0, bits, VT2, Hpart, zpart, N, O, N / 16);
    // 14. finalize 2 -> out
    hipLaunchKernelGGL(fin2_k, dim3(N * O / 256), dim3(256), 0, stream, Hpart, zpart, (float*)d_out, N);
}